// Round 6
// baseline (168.381 us; speedup 1.0000x reference)
//
#include <hip/hip_runtime.h>
#include <stdint.h>

#define N_WORDS 8192
#define LOG2E_8 0.18033688011112043f   // log2(e)/sqrt(64)

typedef __attribute__((ext_vector_type(8))) short short8;
typedef __attribute__((ext_vector_type(4))) float f32x4;
typedef __attribute__((ext_vector_type(16))) float f32x16;
typedef __attribute__((ext_vector_type(2))) __fp16 pkhalf2;   // cvt_pkrtz return type
typedef __attribute__((ext_vector_type(4))) _Float16 half4;
typedef __attribute__((ext_vector_type(8))) _Float16 half8;

__device__ __forceinline__ unsigned short f32_to_bf16(float f) {
    union { float f; unsigned u; } v; v.f = f;
    unsigned u = v.u;
    return (unsigned short)((u + 0x7FFFu + ((u >> 16) & 1u)) >> 16);
}

__device__ __forceinline__ unsigned short f32_to_f16(float f) {
    union { _Float16 h; unsigned short u; } cv;
    cv.h = (_Float16)f;
    return cv.u;
}

// global -> LDS direct copy, 16B per lane. LDS dest must be wave-uniform base;
// HW adds lane*16. Global ptr is per-lane.
__device__ __forceinline__ void async16(const void* g, void* l) {
    __builtin_amdgcn_global_load_lds(
        (const __attribute__((address_space(1))) unsigned int*)g,
        (__attribute__((address_space(3))) unsigned int*)l, 16, 0, 0);
}

// ---------------------------------------------------------------------------
// Kernel 1: QKV projection, SINGLE PASS over x (was 3 passes = 48 MB read;
// now 16 MB). Blocks 0-127: m-tile of 64 rows; per k-block stage x ONCE and
// multiply against wq, wk, wv (acc[3][4]). Blocks 128-255: w_o_eff fold
// weT[j][p] = (f16) sum_h wo[h*64+p][j].
// Outputs:
//   qB bf16 [row][64], cols XOR-swizzled in 8-elem chunks, pre-scaled by
//      log2e/8 (folds softmax scale + exp2 base change)
//   kB bf16, same swizzle
//   vH f16 [vcol][8192], rows swizzled per 64-row group
// Swizzle: chunk c (8 elems) of row r stored at position c ^ (r&7).
// ---------------------------------------------------------------------------
__global__ __launch_bounds__(256) void qkv_gemm(
    const float* __restrict__ x,
    const float* __restrict__ wq, const float* __restrict__ wk,
    const float* __restrict__ wv, const float* __restrict__ wo,
    unsigned short* __restrict__ qB, unsigned short* __restrict__ kB,
    unsigned short* __restrict__ vH, unsigned short* __restrict__ weT)
{
    int t = threadIdx.x;
    int bid = blockIdx.x;

    if (bid >= 128) {
        // w_o_eff fold: coalesced reads over j; f16 transposed scatter store
        int i = (bid - 128) * 256 + t;
        int p = i >> 9;
        int j = i & 511;
        float s = 0.0f;
#pragma unroll
        for (int h = 0; h < 8; ++h) s += wo[(size_t)(h * 64 + p) * 512 + j];
        weT[(size_t)j * 64 + p] = f32_to_f16(s);
        return;
    }

    __shared__ __align__(16) unsigned short ldsX[64 * 72];     // [m][k] pitch 72
    __shared__ __align__(16) unsigned short ldsW[3][64 * 72];  // [mat][n][k]

    int mt = bid;
    const float* wmat[3] = {wq, wk, wv};

    int wvid = t >> 6, lane = t & 63;
    int lq = lane & 15, quad = lane >> 4;

    f32x4 acc[3][4];
#pragma unroll
    for (int mat = 0; mat < 3; ++mat)
#pragma unroll
        for (int nt = 0; nt < 4; ++nt) acc[mat][nt] = (f32x4){0.f, 0.f, 0.f, 0.f};

    // prefetch registers
    float4 xr[4];
    float wr[3][16];
    int wn = t & 63, wkbs = (t >> 6) * 16;

    // prologue: load tile kb=0
    {
#pragma unroll
        for (int j2 = 0; j2 < 4; ++j2) {
            int i = t + j2 * 256;
            int row = i >> 4, c4 = (i & 15) * 4;
            xr[j2] = *(const float4*)(x + (size_t)(mt * 64 + row) * 512 + c4);
        }
#pragma unroll
        for (int mat = 0; mat < 3; ++mat)
#pragma unroll
            for (int kk = 0; kk < 16; ++kk)
                wr[mat][kk] = wmat[mat][(size_t)(wkbs + kk) * 64 + wn];
    }

    for (int kb = 0; kb < 8; ++kb) {
        __syncthreads();   // all waves finished reading LDS of previous tile
        // store prefetched registers -> LDS (f32 -> bf16)
#pragma unroll
        for (int j2 = 0; j2 < 4; ++j2) {
            int i = t + j2 * 256;
            int row = i >> 4, c4 = (i & 15) * 4;
            unsigned p0 = f32_to_bf16(xr[j2].x) | ((unsigned)f32_to_bf16(xr[j2].y) << 16);
            unsigned p1 = f32_to_bf16(xr[j2].z) | ((unsigned)f32_to_bf16(xr[j2].w) << 16);
            *(uint2*)(&ldsX[row * 72 + c4]) = make_uint2(p0, p1);
        }
#pragma unroll
        for (int mat = 0; mat < 3; ++mat)
#pragma unroll
            for (int kk = 0; kk < 16; kk += 2) {
                unsigned p = f32_to_bf16(wr[mat][kk]) |
                             ((unsigned)f32_to_bf16(wr[mat][kk + 1]) << 16);
                *(unsigned*)(&ldsW[mat][wn * 72 + wkbs + kk]) = p;
            }
        __syncthreads();

        // issue next tile's global loads early; they complete under the MFMAs
        if (kb < 7) {
            int k0 = (kb + 1) * 64;
#pragma unroll
            for (int j2 = 0; j2 < 4; ++j2) {
                int i = t + j2 * 256;
                int row = i >> 4, c4 = (i & 15) * 4;
                xr[j2] = *(const float4*)(x + (size_t)(mt * 64 + row) * 512 + k0 + c4);
            }
#pragma unroll
            for (int mat = 0; mat < 3; ++mat)
#pragma unroll
                for (int kk = 0; kk < 16; ++kk)
                    wr[mat][kk] = wmat[mat][(size_t)(k0 + wkbs + kk) * 64 + wn];
        }

        int m = wvid * 16 + lq;
        short8 a0 = *(const short8*)(&ldsX[m * 72 + quad * 8]);
        short8 a1 = *(const short8*)(&ldsX[m * 72 + 32 + quad * 8]);
#pragma unroll
        for (int mat = 0; mat < 3; ++mat)
#pragma unroll
            for (int nt = 0; nt < 4; ++nt) {
                short8 b0 = *(const short8*)(&ldsW[mat][(nt * 16 + lq) * 72 + quad * 8]);
                short8 b1 = *(const short8*)(&ldsW[mat][(nt * 16 + lq) * 72 + 32 + quad * 8]);
                acc[mat][nt] = __builtin_amdgcn_mfma_f32_16x16x32_bf16(a0, b0, acc[mat][nt], 0, 0, 0);
                acc[mat][nt] = __builtin_amdgcn_mfma_f32_16x16x32_bf16(a1, b1, acc[mat][nt], 0, 0, 0);
            }
    }

    int mrow_base = mt * 64 + wvid * 16;
#pragma unroll
    for (int nt = 0; nt < 4; ++nt) {
#pragma unroll
        for (int r = 0; r < 4; ++r) {
            int row = mrow_base + quad * 4 + r;
            int n = nt * 16 + lq;
            int col = ((((n >> 3) ^ (row & 7)) << 3)) | (n & 7);
            qB[(size_t)row * 64 + col] = f32_to_bf16(acc[0][nt][r] * LOG2E_8);
            kB[(size_t)row * 64 + col] = f32_to_bf16(acc[1][nt][r]);
            int rs = (row & ~63) | (((((row >> 3) & 7) ^ (n & 7)) << 3)) | (row & 7);
            vH[(size_t)n * N_WORDS + rs] = f32_to_f16(acc[2][nt][r]);
        }
    }
}

// ---------------------------------------------------------------------------
// Kernel 2: fixed-max flash attention partials, 32x32 MFMA shapes.
// R6 (traffic engineering; R5 showed attn is fabric-BW-bound with zero
// reuse: FETCH ~= logical reads, WRITE 5x inflated by scattered 2B stores):
//  - 512 q-rows per block (1024 thr = 16 waves, each wave 32 q-rows; per-wave
//    code identical to R5). grid (16 q-blocks, S=16) = 256 blocks = 1/CU,
//    4 waves/SIMD. K/V logical reads halve to 32 MB; each staged tile serves
//    4x the q-rows of R4.
//  - pOh epilogue through LDS (reusing the K/V buffers): contiguous
//    128-B-line stores instead of scattered ushort stores.
// S^T = K.Q^T with 32x32x16 bf16; C-layout feeds 32x32x16 f16 PV directly
// under the permuted logical-k mapping (verified R4/R5). lsum on the VALU.
// ---------------------------------------------------------------------------
__global__ __launch_bounds__(1024, 4) void attn_kernel(
    const unsigned short* __restrict__ qB,
    const unsigned short* __restrict__ kB,
    const unsigned short* __restrict__ vH,
    unsigned short* __restrict__ pOh, float* __restrict__ pl, int nk)
{
    // 64 KB: [0..16384) K dbuf, [16384..32768) V dbuf (ushort units);
    // reused wholesale as the 512x64 f16 O staging tile in the epilogue.
    __shared__ __align__(16) unsigned short ldsA[32768];

    int t = threadIdx.x;
    int wvid = t >> 6, lane = t & 63;
    int l31 = lane & 31, hi = lane >> 5;
    int qbase = blockIdx.x * 512;
    int mbase = qbase + wvid * 32;
    int n0 = blockIdx.y * nk;

    // Q B-frags: qrow = mbase + l31; QK step c needs k-chunk (2c+hi)^(qrow&7)
    short8 qf[4];
    {
        int qrow = mbase + l31;
        const unsigned short* qr = qB + (size_t)qrow * 64;
        int s7 = qrow & 7;
#pragma unroll
        for (int c = 0; c < 4; ++c)
            qf[c] = *(const short8*)(qr + (((2 * c + hi) ^ s7) << 3));
    }

    f32x16 zero16;
#pragma unroll
    for (int i = 0; i < 16; ++i) zero16[i] = 0.f;
    f32x16 oacc[2];
    oacc[0] = zero16;
    oacc[1] = zero16;
    float lsum = 0.f;

    auto stage = [&](int buf, int nb) {
        // K tile: 16KB contiguous in global (swizzle baked in); 1024 lanes,
        // one 16B slot each. Per-wave LDS base, HW adds lane*16.
        const char* gK = (const char*)kB + (size_t)nb * 128;
        async16(gK + (size_t)t * 16,
                (char*)(ldsA + buf * 8192) + (size_t)wvid * 1024);
        // V tile: 64 vcols x 128 krows (2 chunk-groups per vcol)
        int vcol = t >> 4, ct = t & 15;
        const char* src = (const char*)vH + (size_t)vcol * 16384 +
                          (size_t)nb * 2 + ((ct >> 3) << 7) + ((ct & 7) << 4);
        async16(src, (char*)(ldsA + 16384 + buf * 8192) + (size_t)wvid * 1024);
    };

    int tiles = nk >> 7;
    stage(0, n0);
    int cur = 0;

    for (int tt = 0; tt < tiles; ++tt) {
        __syncthreads();   // vmcnt(0) drain + barrier: buf[cur] ready,
                           // everyone done reading buf[cur^1]
        if (tt + 1 < tiles) stage(cur ^ 1, n0 + (tt + 1) * 128);

        __builtin_amdgcn_s_setprio(1);
        const unsigned short* K = ldsA + cur * 8192;
        const unsigned short* V = ldsA + 16384 + cur * 8192;

#pragma unroll
        for (int nt = 0; nt < 4; ++nt) {
            // S^T 32x32 tile: A = K rows nt*32+l31, B = Q; 4 K-chunks of 16
            const unsigned short* kr = K + (nt * 32 + l31) * 64;
            int s7 = l31 & 7;
            f32x16 st = zero16;
#pragma unroll
            for (int c = 0; c < 4; ++c) {
                short8 a = *(const short8*)(kr + (((2 * c + hi) ^ s7) << 3));
                st = __builtin_amdgcn_mfma_f32_32x32x16_bf16(a, qf[c], st, 0, 0, 0);
            }

            // p = exp2(s); lsum on VALU; pack regs IN ORDER -> two A half8s
            union { half8 v8[2]; pkhalf2 v2[8]; } pa;
#pragma unroll
            for (int p = 0; p < 8; ++p) {
                float e0 = exp2f(st[2 * p]);
                float e1 = exp2f(st[2 * p + 1]);
                lsum += e0 + e1;
                pa.v2[p] = __builtin_amdgcn_cvt_pkrtz(e0, e1);
            }

            // PV: per half m, B = V chunks (4nt+2m, 4nt+2m+1) at offset hi*4
#pragma unroll
            for (int m = 0; m < 2; ++m) {
                int c0 = 4 * nt + 2 * m;
                int c1 = c0 + 1;
#pragma unroll
                for (int vt = 0; vt < 2; ++vt) {
                    int vcol = vt * 32 + l31;
                    int cs0 = (c0 & 8) | ((c0 & 7) ^ (vcol & 7));
                    int cs1 = (c1 & 8) | ((c1 & 7) ^ (vcol & 7));
                    union { half8 v8; half4 v4[2]; } vb;
                    vb.v4[0] = *(const half4*)(V + vcol * 128 + (cs0 << 3) + hi * 4);
                    vb.v4[1] = *(const half4*)(V + vcol * 128 + (cs1 << 3) + hi * 4);
                    oacc[vt] = __builtin_amdgcn_mfma_f32_32x32x16_f16(
                        pa.v8[m], vb.v8, oacc[vt], 0, 0, 0);
                }
            }
        }
        __builtin_amdgcn_s_setprio(0);
        cur ^= 1;
    }

    // each (l31) qrow's partial sum lives split across lane-halves
    lsum += __shfl_xor(lsum, 32);

    size_t obase = (size_t)blockIdx.y * N_WORDS;
    if (hi == 0) pl[obase + mbase + l31] = lsum;

    // ---- coalesced O epilogue: stage f16 O in LDS, store full 128-B lines
    __syncthreads();   // all waves done reading K/V
#pragma unroll
    for (int vt = 0; vt < 2; ++vt)
#pragma unroll
        for (int r = 0; r < 16; ++r) {
            int lrow = wvid * 32 + (r & 3) + 8 * (r >> 2) + 4 * hi;
            ldsA[lrow * 64 + vt * 32 + l31] = f32_to_f16(oacc[vt][r]);
        }
    __syncthreads();
    {
        const uint4* U = (const uint4*)ldsA;
        uint4* G = (uint4*)(pOh + (obase + qbase) * 64);
#pragma unroll
        for (int j = 0; j < 4; ++j)
            G[t + 1024 * j] = U[t + 1024 * j];
    }
}

// ---------------------------------------------------------------------------
// Kernel 3: combine + output GEMM fused, GEMM on the MFMA pipe.
// Per block (16 rows): reduce the S split partials (f16 in, f32 accum) into a
// padded f16 LDS tile, then out = head @ weT via 16x16x32 f16 MFMA
// (A = head rows from LDS; B = weT streamed from L2, 64KB, shared by all
// blocks).
// ---------------------------------------------------------------------------
__global__ __launch_bounds__(256) void out_kernel(
    const unsigned short* __restrict__ pOh, const float* __restrict__ pl,
    const unsigned short* __restrict__ weT, float* __restrict__ out, int S)
{
    __shared__ __align__(16) _Float16 ldsH[16 * 72];  // [row][k] pitch 72
    int t = threadIdx.x;
    int r0 = blockIdx.x * 16;
    const _Float16* pOf = (const _Float16*)pOh;

    // combine: 16 rows x 64 dims; per wave: row fixed, d = lane (coalesced)
#pragma unroll
    for (int j = 0; j < 4; ++j) {
        int i = t + j * 256;
        int row = i >> 6, d = i & 63;
        float so = 0.f, sl = 0.f;
        for (int s = 0; s < S; ++s) {
            so += (float)pOf[((size_t)s * N_WORDS + r0 + row) * 64 + d];
            sl += pl[(size_t)s * N_WORDS + r0 + row];
        }
        ldsH[row * 72 + d] = (_Float16)(so / sl);
    }
    __syncthreads();

    int wv = t >> 6, lane = t & 63;
    int lq = lane & 15, quad = lane >> 4;

    // A-frag: head row = lq, k = quad*8+j (+32 for a1)
    half8 a0 = *(const half8*)(&ldsH[lq * 72 + quad * 8]);
    half8 a1 = *(const half8*)(&ldsH[lq * 72 + 32 + quad * 8]);
    const _Float16* wT = (const _Float16*)weT;

#pragma unroll
    for (int ntl = 0; ntl < 8; ++ntl) {
        int nt = wv * 8 + ntl;
        const _Float16* wrow = wT + (size_t)(nt * 16 + lq) * 64;
        half8 b0 = *(const half8*)(wrow + quad * 8);
        half8 b1 = *(const half8*)(wrow + 32 + quad * 8);
        f32x4 acc = (f32x4){0.f, 0.f, 0.f, 0.f};
        acc = __builtin_amdgcn_mfma_f32_16x16x32_f16(a0, b0, acc, 0, 0, 0);
        acc = __builtin_amdgcn_mfma_f32_16x16x32_f16(a1, b1, acc, 0, 0, 0);
#pragma unroll
        for (int r = 0; r < 4; ++r)
            out[(size_t)(r0 + quad * 4 + r) * 512 + nt * 16 + lq] = acc[r];
    }
}

// ---------------------------------------------------------------------------
extern "C" void kernel_launch(void* const* d_in, const int* in_sizes, int n_in,
                              void* d_out, int out_size, void* d_ws, size_t ws_size,
                              hipStream_t stream)
{
    const float* x  = (const float*)d_in[0];
    const float* wq = (const float*)d_in[1];
    const float* wk = (const float*)d_in[2];
    const float* wv = (const float*)d_in[3];
    const float* wo = (const float*)d_in[4];
    float* out = (float*)d_out;

    char* ws = (char*)d_ws;
    unsigned short* qB  = (unsigned short*)(ws);                   // 1 MB
    unsigned short* kB  = (unsigned short*)(ws + 1048576);         // 1 MB
    unsigned short* vH  = (unsigned short*)(ws + 2097152);         // 1 MB
    unsigned short* weT = (unsigned short*)(ws + 3145728);         // 64 KB
    float* pl           = (float*)(ws + 3211264);                  // S*32 KB (<=512 KB)
    unsigned short* pOh = (unsigned short*)(ws + 3735552);         // S*1 MB

    // S splits: 16 (grid 256 = 1 block/CU at 1024 thr) if workspace allows,
    // else 8, else 4.
    size_t base = 3735552;
    int S = (ws_size >= base + 16u * 1048576u) ? 16
          : (ws_size >= base + 8u * 1048576u) ? 8 : 4;
    int nk = N_WORDS / S;

    hipLaunchKernelGGL(qkv_gemm, dim3(256), dim3(256), 0, stream,
                       x, wq, wk, wv, wo, qB, kB, vH, weT);
    hipLaunchKernelGGL(attn_kernel, dim3(16, S), dim3(1024), 0, stream,
                       qB, kB, vH, pOh, pl, nk);
    hipLaunchKernelGGL(out_kernel, dim3(512), dim3(256), 0, stream,
                       pOh, pl, weT, out, S);
}

// Round 8
// 129.848 us; speedup vs baseline: 1.2968x; 1.2968x over previous
//
#include <hip/hip_runtime.h>
#include <stdint.h>

#define N_WORDS 8192
#define LOG2E_8 0.18033688011112043f   // log2(e)/sqrt(64)

typedef __attribute__((ext_vector_type(8))) short short8;
typedef __attribute__((ext_vector_type(4))) float f32x4;
typedef __attribute__((ext_vector_type(16))) float f32x16;
typedef __attribute__((ext_vector_type(2))) __fp16 pkhalf2;   // cvt_pkrtz return type
typedef __attribute__((ext_vector_type(4))) _Float16 half4;
typedef __attribute__((ext_vector_type(8))) _Float16 half8;

__device__ __forceinline__ unsigned short f32_to_bf16(float f) {
    union { float f; unsigned u; } v; v.f = f;
    unsigned u = v.u;
    return (unsigned short)((u + 0x7FFFu + ((u >> 16) & 1u)) >> 16);
}

__device__ __forceinline__ unsigned short f32_to_f16(float f) {
    union { _Float16 h; unsigned short u; } cv;
    cv.h = (_Float16)f;
    return cv.u;
}

// global -> LDS direct copy, 16B per lane. LDS dest must be wave-uniform base;
// HW adds lane*16. Global ptr is per-lane.
__device__ __forceinline__ void async16(const void* g, void* l) {
    __builtin_amdgcn_global_load_lds(
        (const __attribute__((address_space(1))) unsigned int*)g,
        (__attribute__((address_space(3))) unsigned int*)l, 16, 0, 0);
}

// ---------------------------------------------------------------------------
// Kernel 1: QKV projection as bf16 MFMA GEMM: [8192x512] @ [512x64] x3 mats,
// plus (blockIdx.y==3) the w_o_eff fold:
//   weT[j][p] = (f16) sum_h wo[h*64+p][j]   (transposed, B-frag ready)
// grid (128, 4), 256 thr -> 512 blocks = 2/CU (validated R5 structure; R6's
// 128-compute-block single-pass left half the chip idle and regressed).
// Register-prefetch pipeline: global loads for tile kb+1 issued while MFMAs
// of tile kb run.
// Outputs:
//   mat0 -> qB bf16 [row][64], cols XOR-swizzled in 8-elem chunks, pre-scaled
//           by log2e/8 (folds softmax scale + exp2 base change)
//   mat1 -> kB bf16, same swizzle
//   mat2 -> vH f16 [vcol][8192], rows swizzled per 64-row group
// Swizzle: chunk c (8 elems) of row r stored at position c ^ (r&7).
// ---------------------------------------------------------------------------
__global__ __launch_bounds__(256) void qkv_gemm(
    const float* __restrict__ x,
    const float* __restrict__ wq, const float* __restrict__ wk,
    const float* __restrict__ wv, const float* __restrict__ wo,
    unsigned short* __restrict__ qB, unsigned short* __restrict__ kB,
    unsigned short* __restrict__ vH, unsigned short* __restrict__ weT)
{
    int t = threadIdx.x;
    int mat = blockIdx.y;

    if (mat == 3) {
        // w_o_eff fold: coalesced reads over j; f16 transposed scatter store
        int i = blockIdx.x * 256 + t;
        int p = i >> 9;
        int j = i & 511;
        float s = 0.0f;
#pragma unroll
        for (int h = 0; h < 8; ++h) s += wo[(size_t)(h * 64 + p) * 512 + j];
        weT[(size_t)j * 64 + p] = f32_to_f16(s);
        return;
    }

    __shared__ __align__(16) unsigned short ldsX[64 * 72];  // [m][k] pitch 72
    __shared__ __align__(16) unsigned short ldsW[64 * 72];  // [n][k] pitch 72

    int mt = blockIdx.x;
    const float* w = (mat == 0) ? wq : (mat == 1) ? wk : wv;

    int wvid = t >> 6, lane = t & 63;
    int lq = lane & 15, quad = lane >> 4;

    f32x4 acc[4];
#pragma unroll
    for (int nt = 0; nt < 4; ++nt) acc[nt] = (f32x4){0.f, 0.f, 0.f, 0.f};

    // prefetch registers
    float4 xr[4];
    float wr[16];
    int wn = t & 63, wkbs = (t >> 6) * 16;

    // prologue: load tile kb=0
    {
#pragma unroll
        for (int j2 = 0; j2 < 4; ++j2) {
            int i = t + j2 * 256;
            int row = i >> 4, c4 = (i & 15) * 4;
            xr[j2] = *(const float4*)(x + (size_t)(mt * 64 + row) * 512 + c4);
        }
#pragma unroll
        for (int kk = 0; kk < 16; ++kk)
            wr[kk] = w[(size_t)(wkbs + kk) * 64 + wn];
    }

    for (int kb = 0; kb < 8; ++kb) {
        __syncthreads();   // all waves finished reading LDS of previous tile
        // store prefetched registers -> LDS (f32 -> bf16)
#pragma unroll
        for (int j2 = 0; j2 < 4; ++j2) {
            int i = t + j2 * 256;
            int row = i >> 4, c4 = (i & 15) * 4;
            unsigned p0 = f32_to_bf16(xr[j2].x) | ((unsigned)f32_to_bf16(xr[j2].y) << 16);
            unsigned p1 = f32_to_bf16(xr[j2].z) | ((unsigned)f32_to_bf16(xr[j2].w) << 16);
            *(uint2*)(&ldsX[row * 72 + c4]) = make_uint2(p0, p1);
        }
#pragma unroll
        for (int kk = 0; kk < 16; kk += 2) {
            unsigned p = f32_to_bf16(wr[kk]) | ((unsigned)f32_to_bf16(wr[kk + 1]) << 16);
            *(unsigned*)(&ldsW[wn * 72 + wkbs + kk]) = p;
        }
        __syncthreads();

        // issue next tile's global loads early; they complete under the MFMAs
        if (kb < 7) {
            int k0 = (kb + 1) * 64;
#pragma unroll
            for (int j2 = 0; j2 < 4; ++j2) {
                int i = t + j2 * 256;
                int row = i >> 4, c4 = (i & 15) * 4;
                xr[j2] = *(const float4*)(x + (size_t)(mt * 64 + row) * 512 + k0 + c4);
            }
#pragma unroll
            for (int kk = 0; kk < 16; ++kk)
                wr[kk] = w[(size_t)(k0 + wkbs + kk) * 64 + wn];
        }

        int m = wvid * 16 + lq;
        short8 a0 = *(const short8*)(&ldsX[m * 72 + quad * 8]);
        short8 a1 = *(const short8*)(&ldsX[m * 72 + 32 + quad * 8]);
#pragma unroll
        for (int nt = 0; nt < 4; ++nt) {
            short8 b0 = *(const short8*)(&ldsW[(nt * 16 + lq) * 72 + quad * 8]);
            short8 b1 = *(const short8*)(&ldsW[(nt * 16 + lq) * 72 + 32 + quad * 8]);
            acc[nt] = __builtin_amdgcn_mfma_f32_16x16x32_bf16(a0, b0, acc[nt], 0, 0, 0);
            acc[nt] = __builtin_amdgcn_mfma_f32_16x16x32_bf16(a1, b1, acc[nt], 0, 0, 0);
        }
    }

    int mrow_base = mt * 64 + wvid * 16;
#pragma unroll
    for (int nt = 0; nt < 4; ++nt) {
#pragma unroll
        for (int r = 0; r < 4; ++r) {
            int row = mrow_base + quad * 4 + r;
            int n = nt * 16 + lq;
            float v = acc[nt][r];
            if (mat == 0) {
                v *= LOG2E_8;
                int col = ((((n >> 3) ^ (row & 7)) << 3)) | (n & 7);
                qB[(size_t)row * 64 + col] = f32_to_bf16(v);
            } else if (mat == 1) {
                int col = ((((n >> 3) ^ (row & 7)) << 3)) | (n & 7);
                kB[(size_t)row * 64 + col] = f32_to_bf16(v);
            } else {
                int rs = (row & ~63) | (((((row >> 3) & 7) ^ (n & 7)) << 3)) | (row & 7);
                vH[(size_t)n * N_WORDS + rs] = f32_to_f16(v);
            }
        }
    }
}

// ---------------------------------------------------------------------------
// Kernel 2: fixed-max flash attention partials, 32x32 MFMA shapes.
// R7 (rerun): validated R4 structure (256 thr = 4 waves x 32 qrows,
// 128 qrows/block, S=8 splits of 1024 krows, 8 tiles, 2 blocks/CU) -- the
// fastest measured (~29us back-solved) -- PLUS split-per-XCD locality:
// 1-D grid of 64*S blocks, s = bid & (S-1), qb = bid >> log2(S). With S=8,
// consecutive block ids round-robin across the 8 XCDs, so ALL blocks with
// the same split s land on ONE XCD: that XCD reads exactly one 256 KB K/V
// slice (L2-resident after first touch, ~34 TB/s re-reads) + 1 MB of qB.
// Fabric traffic for K/V drops from ~100 MB (replicated across XCDs) to
// ~2 MB + 8 MB qB.
// S^T = K.Q^T with 32x32x16 bf16; C-layout feeds 32x32x16 f16 PV directly
// under the permuted logical-k mapping (verified R4-R6). lsum on the VALU.
// pOh epilogue LDS-staged (reuses ldsK[0]) -> contiguous 16B/lane stores.
// ---------------------------------------------------------------------------
__global__ __launch_bounds__(256) void attn_kernel(
    const unsigned short* __restrict__ qB,
    const unsigned short* __restrict__ kB,
    const unsigned short* __restrict__ vH,
    unsigned short* __restrict__ pOh, float* __restrict__ pl,
    int nk, int sshift)
{
    __shared__ __align__(16) unsigned short ldsK[2][128 * 64];
    __shared__ __align__(16) unsigned short ldsV[2][64 * 128];

    int t = threadIdx.x;
    int bid = blockIdx.x;
    int s = bid & ((1 << sshift) - 1);   // split  -> fixed XCD (round-robin)
    int qb = bid >> sshift;              // q-block within split
    int wvid = t >> 6, lane = t & 63;
    int l31 = lane & 31, hi = lane >> 5;
    int mbase = qb * 128 + wvid * 32;
    int n0 = s * nk;

    // Q B-frags: qrow = mbase + l31; QK step c needs k-chunk (2c+hi)^(qrow&7)
    short8 qf[4];
    {
        int qrow = mbase + l31;
        const unsigned short* qr = qB + (size_t)qrow * 64;
        int s7 = qrow & 7;
#pragma unroll
        for (int c = 0; c < 4; ++c)
            qf[c] = *(const short8*)(qr + (((2 * c + hi) ^ s7) << 3));
    }

    f32x16 zero16;
#pragma unroll
    for (int i = 0; i < 16; ++i) zero16[i] = 0.f;
    f32x16 oacc[2];
    oacc[0] = zero16;
    oacc[1] = zero16;
    float lsum = 0.f;

    auto stage = [&](int buf, int nb) {
        // K tile: 16KB contiguous in global (swizzle baked in)
        const char* gK = (const char*)kB + (size_t)nb * 128;
#pragma unroll
        for (int i = 0; i < 4; ++i) {
            int L0 = (wvid * 4 + i) * 64;
            async16(gK + (size_t)(L0 + lane) * 16, (char*)ldsK[buf] + (size_t)L0 * 16);
        }
        // V tile: 64 vcols x 128 krows (2 chunk-groups per vcol)
#pragma unroll
        for (int i = 0; i < 4; ++i) {
            int L0 = (wvid * 4 + i) * 64;
            int L = L0 + lane;
            int vcol = L >> 4, ct = L & 15;
            const char* src = (const char*)vH + (size_t)vcol * 16384 +
                              (size_t)nb * 2 + ((ct >> 3) << 7) + ((ct & 7) << 4);
            async16(src, (char*)ldsV[buf] + (size_t)L0 * 16);
        }
    };

    int tiles = nk >> 7;
    stage(0, n0);
    int cur = 0;

    for (int tt = 0; tt < tiles; ++tt) {
        __syncthreads();   // vmcnt(0) drain + barrier: buf[cur] ready,
                           // everyone done reading buf[cur^1]
        if (tt + 1 < tiles) stage(cur ^ 1, n0 + (tt + 1) * 128);

        __builtin_amdgcn_s_setprio(1);
        const unsigned short* K = ldsK[cur];
        const unsigned short* V = ldsV[cur];

#pragma unroll
        for (int nt = 0; nt < 4; ++nt) {
            // S^T 32x32 tile: A = K rows nt*32+l31, B = Q; 4 K-chunks of 16
            const unsigned short* kr = K + (nt * 32 + l31) * 64;
            int s7 = l31 & 7;
            f32x16 st = zero16;
#pragma unroll
            for (int c = 0; c < 4; ++c) {
                short8 a = *(const short8*)(kr + (((2 * c + hi) ^ s7) << 3));
                st = __builtin_amdgcn_mfma_f32_32x32x16_bf16(a, qf[c], st, 0, 0, 0);
            }

            // p = exp2(s); lsum on VALU; pack regs IN ORDER -> two A half8s
            union { half8 v8[2]; pkhalf2 v2[8]; } pa;
#pragma unroll
            for (int p = 0; p < 8; ++p) {
                float e0 = exp2f(st[2 * p]);
                float e1 = exp2f(st[2 * p + 1]);
                lsum += e0 + e1;
                pa.v2[p] = __builtin_amdgcn_cvt_pkrtz(e0, e1);
            }

            // PV: per half m, B = V chunks (4nt+2m, 4nt+2m+1) at offset hi*4
#pragma unroll
            for (int m = 0; m < 2; ++m) {
                int c0 = 4 * nt + 2 * m;
                int c1 = c0 + 1;
#pragma unroll
                for (int vt = 0; vt < 2; ++vt) {
                    int vcol = vt * 32 + l31;
                    int cs0 = (c0 & 8) | ((c0 & 7) ^ (vcol & 7));
                    int cs1 = (c1 & 8) | ((c1 & 7) ^ (vcol & 7));
                    union { half8 v8; half4 v4[2]; } vb;
                    vb.v4[0] = *(const half4*)(V + vcol * 128 + (cs0 << 3) + hi * 4);
                    vb.v4[1] = *(const half4*)(V + vcol * 128 + (cs1 << 3) + hi * 4);
                    oacc[vt] = __builtin_amdgcn_mfma_f32_32x32x16_f16(
                        pa.v8[m], vb.v8, oacc[vt], 0, 0, 0);
                }
            }
        }
        __builtin_amdgcn_s_setprio(0);
        cur ^= 1;
    }

    // each (l31) qrow's partial sum lives split across lane-halves
    lsum += __shfl_xor(lsum, 32);

    size_t obase = (size_t)s * N_WORDS;
    if (hi == 0) pl[obase + mbase + l31] = lsum;

    // ---- coalesced O epilogue: stage f16 O in LDS, store 16B/lane lines
    __syncthreads();   // all waves done reading K/V of the last tile
    unsigned short* ldsO = &ldsK[0][0];   // 128x64 f16 = 16 KB
#pragma unroll
    for (int vt = 0; vt < 2; ++vt)
#pragma unroll
        for (int r = 0; r < 16; ++r) {
            int lrow = wvid * 32 + (r & 3) + 8 * (r >> 2) + 4 * hi;
            ldsO[lrow * 64 + vt * 32 + l31] = f32_to_f16(oacc[vt][r]);
        }
    __syncthreads();
    {
        const uint4* U = (const uint4*)ldsO;
        uint4* G = (uint4*)(pOh + (obase + (size_t)qb * 128) * 64);
#pragma unroll
        for (int j = 0; j < 4; ++j)
            G[t + 256 * j] = U[t + 256 * j];
    }
}

// ---------------------------------------------------------------------------
// Kernel 3: combine + output GEMM fused, GEMM on the MFMA pipe.
// Per block (16 rows): reduce the S split partials (f16 in, f32 accum) into a
// padded f16 LDS tile, then out = head @ weT via 16x16x32 f16 MFMA
// (A = head rows from LDS; B = weT streamed from L2, 64KB, shared by all
// blocks).
// ---------------------------------------------------------------------------
__global__ __launch_bounds__(256) void out_kernel(
    const unsigned short* __restrict__ pOh, const float* __restrict__ pl,
    const unsigned short* __restrict__ weT, float* __restrict__ out, int S)
{
    __shared__ __align__(16) _Float16 ldsH[16 * 72];  // [row][k] pitch 72
    int t = threadIdx.x;
    int r0 = blockIdx.x * 16;
    const _Float16* pOf = (const _Float16*)pOh;

    // combine: 16 rows x 64 dims; per wave: row fixed, d = lane (coalesced)
#pragma unroll
    for (int j = 0; j < 4; ++j) {
        int i = t + j * 256;
        int row = i >> 6, d = i & 63;
        float so = 0.f, sl = 0.f;
        for (int s = 0; s < S; ++s) {
            so += (float)pOf[((size_t)s * N_WORDS + r0 + row) * 64 + d];
            sl += pl[(size_t)s * N_WORDS + r0 + row];
        }
        ldsH[row * 72 + d] = (_Float16)(so / sl);
    }
    __syncthreads();

    int wv = t >> 6, lane = t & 63;
    int lq = lane & 15, quad = lane >> 4;

    // A-frag: head row = lq, k = quad*8+j (+32 for a1)
    half8 a0 = *(const half8*)(&ldsH[lq * 72 + quad * 8]);
    half8 a1 = *(const half8*)(&ldsH[lq * 72 + 32 + quad * 8]);
    const _Float16* wT = (const _Float16*)weT;

#pragma unroll
    for (int ntl = 0; ntl < 8; ++ntl) {
        int nt = wv * 8 + ntl;
        const _Float16* wrow = wT + (size_t)(nt * 16 + lq) * 64;
        half8 b0 = *(const half8*)(wrow + quad * 8);
        half8 b1 = *(const half8*)(wrow + 32 + quad * 8);
        f32x4 acc = (f32x4){0.f, 0.f, 0.f, 0.f};
        acc = __builtin_amdgcn_mfma_f32_16x16x32_f16(a0, b0, acc, 0, 0, 0);
        acc = __builtin_amdgcn_mfma_f32_16x16x32_f16(a1, b1, acc, 0, 0, 0);
#pragma unroll
        for (int r = 0; r < 4; ++r)
            out[(size_t)(r0 + quad * 4 + r) * 512 + nt * 16 + lq] = acc[r];
    }
}

// ---------------------------------------------------------------------------
extern "C" void kernel_launch(void* const* d_in, const int* in_sizes, int n_in,
                              void* d_out, int out_size, void* d_ws, size_t ws_size,
                              hipStream_t stream)
{
    const float* x  = (const float*)d_in[0];
    const float* wq = (const float*)d_in[1];
    const float* wk = (const float*)d_in[2];
    const float* wv = (const float*)d_in[3];
    const float* wo = (const float*)d_in[4];
    float* out = (float*)d_out;

    char* ws = (char*)d_ws;
    unsigned short* qB  = (unsigned short*)(ws);                   // 1 MB
    unsigned short* kB  = (unsigned short*)(ws + 1048576);         // 1 MB
    unsigned short* vH  = (unsigned short*)(ws + 2097152);         // 1 MB
    unsigned short* weT = (unsigned short*)(ws + 3145728);         // 64 KB
    float* pl           = (float*)(ws + 3211264);                  // S*32 KB
    unsigned short* pOh = (unsigned short*)(ws + 3735552);         // S*1 MB

    // S=8 (one split per XCD) if workspace allows, else 4.
    size_t base = 3735552;
    int S = (ws_size >= base + 8u * 1048576u) ? 8 : 4;
    int sshift = (S == 8) ? 3 : 2;
    int nk = N_WORDS / S;

    hipLaunchKernelGGL(qkv_gemm, dim3(128, 4), dim3(256), 0, stream,
                       x, wq, wk, wv, wo, qB, kB, vH, weT);
    hipLaunchKernelGGL(attn_kernel, dim3(64 * S), dim3(256), 0, stream,
                       qB, kB, vH, pOh, pl, nk, sshift);
    hipLaunchKernelGGL(out_kernel, dim3(512), dim3(256), 0, stream,
                       pOh, pl, weT, out, S);
}